// Round 6
// baseline (219.283 us; speedup 1.0000x reference)
//
#include <hip/hip_runtime.h>

#define HH 128
#define WW 128
#define CC 64
#define OO 64
#define KK 9
#define PLANE (HH * WW)

#define DESC_UNITS (KK * 128)               // 1152 units (k, p) for one row
#define LDS_TOTAL (DESC_UNITS * 16)         // 18432 B -> 3+ blocks/CU

typedef _Float16 half8v __attribute__((ext_vector_type(8)));
typedef _Float16 half2v __attribute__((ext_vector_type(2)));
typedef float floatx4 __attribute__((ext_vector_type(4)));

__device__ __forceinline__ unsigned pkpair(float a, float b) {
    return __builtin_bit_cast(unsigned, __builtin_amdgcn_cvt_pkrtz(a, b));
}
__device__ __forceinline__ half2v h2(unsigned u) {
    return __builtin_bit_cast(half2v, u);
}

// ---------- combined prep: blocks [0,2048) NCHW->split-half NHWC f16; [2048,2192) weight ----------
__global__ __launch_bounds__(256)
void prep_kernel(const float* __restrict__ in, const float* __restrict__ wsrc,
                 unsigned short* __restrict__ outT, _Float16* __restrict__ wt4) {
    __shared__ unsigned tile[64 * 36];
    int blk = blockIdx.x;
    int t = threadIdx.x;
    if (blk < 2048) {
        int b = blk & 7;                     // XCD swizzle
        int rest = blk >> 3;
        int y = rest >> 1;
        int xh = rest & 1;
        int p = t & 63;
        int cg = t >> 6;                     // 0..3
        const float* src = in + (size_t)(b * 64) * PLANE + y * WW + xh * 64 + p;
#pragma unroll
        for (int i = 0; i < 8; ++i) {
            int c0 = cg * 16 + 2 * i;
            float v0 = src[(size_t)c0 * PLANE];
            float v1 = src[(size_t)(c0 + 1) * PLANE];
            unsigned lo = __builtin_bit_cast(unsigned short, (_Float16)v0);
            unsigned hi = __builtin_bit_cast(unsigned short, (_Float16)v1);
            tile[p * 36 + (c0 >> 1)] = lo | (hi << 16);
        }
        __syncthreads();
        int p2 = t >> 2;                     // px 0..63
        int q = t & 3;                       // ch-16 group
        const unsigned* s = &tile[p2 * 36 + q * 8];
        uint4 w0 = *(const uint4*)s;
        uint4 w1 = *(const uint4*)(s + 4);
        int half = q >> 1;
        char* dst = (char*)outT + ((size_t)(b * 2 + half) << 20)
                  + (size_t)(y * 128 + xh * 64 + p2) * 64 + (q & 1) * 32;
        *(uint4*)dst = w0;
        *(uint4*)(dst + 16) = w1;
    } else {
        int idx = (blk - 2048) * 256 + t;
        if (idx < 2 * KK * 4 * 64 * 8) {
            int j = idx & 7;
            int lane = (idx >> 3) & 63;
            int nt = (idx >> 9) & 3;
            int pk = idx >> 11;              // pass*9 + k
            int k = pk % 9;
            int pass = pk / 9;
            int o = nt * 16 + (lane & 15);
            int c = pass * 32 + (lane >> 4) * 8 + j;
            wt4[idx] = (_Float16)wsrc[(o * 64 + c) * 9 + k];
        }
    }
}

// ---------- main: one row per 512-thread block, L2-direct gather, LDS = descriptors only ----------
// dataT (2MB/batch) is XCD-L2-resident, so taps read straight from global (L2 ~250cyc) instead
// of a barrier-fenced LDS band. 18KB LDS -> 3 blocks/CU resident, no barriers in the k-loop;
// TLP (24 waves/CU) hides tap latency. Pool/overflow machinery eliminated: any clamped row is
// a valid in-plane address and zero-weight taps contribute 0.
__global__ __launch_bounds__(512, 6)
void deform_mfma_kernel(const unsigned short* __restrict__ dataT,
                        const float* __restrict__ offset,
                        const _Float16* __restrict__ wt4,
                        float* __restrict__ out) {
    __shared__ __align__(16) char SB[LDS_TOTAL];

    const int t = threadIdx.x;
    const int lane = t & 63;
    const int w = t >> 6;                // wave 0..7
    const unsigned quad = (unsigned)((lane >> 4) & 3);
    const int l15 = lane & 15;
    const int raw = blockIdx.x;
    const int b = raw & 7;               // XCD-aligned batch
    const int ho = raw >> 3;             // row 0..127

    // ---- descriptors: 1152 (k, p) units over 512 threads ----
#pragma unroll
    for (int i = 0; i < 3; ++i) {
        int u = i * 512 + t;
        if (u < DESC_UNITS) {
            int x = u & 127;
            int k = u >> 7;
            const float* offp = offset + ((size_t)(b * 18) + 2 * k) * PLANE + ho * WW + x;
            float oy = offp[0];
            float ox = offp[PLANE];
            float py = (float)(ho - 1 + k / 3) + oy;
            float pxx = (float)(x - 1 + k % 3) + ox;
            float y0f = floorf(py);
            float x0f = floorf(pxx);
            float fy = py - y0f;
            float fx = pxx - x0f;
            int y0 = (int)y0f, x0 = (int)x0f;
            int y1 = y0 + 1, x1 = x0 + 1;
            float wy0 = (1.f - fy) * ((y0 >= 0 && y0 < HH) ? 1.f : 0.f);
            float wy1 = fy * ((y1 >= 0 && y1 < HH) ? 1.f : 0.f);
            float wx0 = (1.f - fx) * ((x0 >= 0 && x0 < WW) ? 1.f : 0.f);
            float wx1 = fx * ((x1 >= 0 && x1 < WW) ? 1.f : 0.f);
            int yc0 = min(max(y0, 0), HH - 1);
            int yc1 = min(max(y1, 0), HH - 1);
            int x_lo = min(max(x0, 0), WW - 2);
            float wA = ((x0 == x_lo) ? wx0 : 0.f) + ((x1 == x_lo) ? wx1 : 0.f);
            float wB = ((x0 == x_lo + 1) ? wx0 : 0.f) + ((x1 == x_lo + 1) ? wx1 : 0.f);

            uint4 d;
            d.x = (unsigned)((yc0 * 128 + x_lo) << 6);  // byte offset of (y0,x_lo) window
            d.w = (unsigned)((yc1 * 128 + x_lo) << 6);  // byte offset of (y1,x_lo) window
            d.y = pkpair(wy0 * wA, wy0 * wB);           // (w00, w01)
            d.z = pkpair(wy1 * wA, wy1 * wB);           // (w10, w11)
            *(uint4*)(SB + (size_t)u * 16) = d;
        }
    }
    __syncthreads();

    floatx4 acc[4];
#pragma unroll
    for (int nt = 0; nt < 4; ++nt)
        acc[nt] = (floatx4){0.f, 0.f, 0.f, 0.f};

    const unsigned qoff = quad * 16;
    const int p = w * 16 + l15;

    for (int pass = 0; pass < 2; ++pass) {
        const char* gh = (const char*)dataT + ((size_t)(b * 2 + pass) << 20);
#pragma unroll
        for (int k = 0; k < KK; ++k) {
            uint4 bfr[4];
            const uint4* wk = (const uint4*)wt4 + (size_t)((pass * 9 + k) * 4) * 64 + lane;
#pragma unroll
            for (int nt = 0; nt < 4; ++nt) bfr[nt] = wk[nt * 64];

            uint4 d = *(const uint4*)(SB + (size_t)(k * 128 + p) * 16);
            half2v wv0 = h2(d.y), wv1 = h2(d.z);
            half2v h00 = __builtin_shufflevector(wv0, wv0, 0, 0);
            half2v h01 = __builtin_shufflevector(wv0, wv0, 1, 1);
            half2v h10 = __builtin_shufflevector(wv1, wv1, 0, 0);
            half2v h11 = __builtin_shufflevector(wv1, wv1, 1, 1);
            const char* r0 = gh + d.x + qoff;
            const char* r1 = gh + d.w + qoff;
            uint4 v00 = *(const uint4*)r0;
            uint4 v01 = *(const uint4*)(r0 + 64);
            uint4 v10 = *(const uint4*)r1;
            uint4 v11 = *(const uint4*)(r1 + 64);
            half2v s0 = h2(v00.x) * h00 + h2(v01.x) * h01 + h2(v10.x) * h10 + h2(v11.x) * h11;
            half2v s1 = h2(v00.y) * h00 + h2(v01.y) * h01 + h2(v10.y) * h10 + h2(v11.y) * h11;
            half2v s2 = h2(v00.z) * h00 + h2(v01.z) * h01 + h2(v10.z) * h10 + h2(v11.z) * h11;
            half2v s3 = h2(v00.w) * h00 + h2(v01.w) * h01 + h2(v10.w) * h10 + h2(v11.w) * h11;
            uint4 sv = make_uint4(__builtin_bit_cast(unsigned, s0),
                                  __builtin_bit_cast(unsigned, s1),
                                  __builtin_bit_cast(unsigned, s2),
                                  __builtin_bit_cast(unsigned, s3));
            half8v afrag = __builtin_bit_cast(half8v, sv);   // A[m=l15][c=quad*8+j]
#pragma unroll
            for (int nt = 0; nt < 4; ++nt)
                acc[nt] = __builtin_amdgcn_mfma_f32_16x16x32_f16(
                    afrag, __builtin_bit_cast(half8v, bfr[nt]), acc[nt], 0, 0, 0);
        }
    }

    // ---- epilogue: D col=lane&15 (=o), row=quad*4+reg (=pixel) ----
#pragma unroll
    for (int nt = 0; nt < 4; ++nt) {
        int o = nt * 16 + l15;
        int x = w * 16 + (int)quad * 4;
        float* dst = out + (size_t)(b * 64 + o) * PLANE + ho * 128 + x;
        *(floatx4*)dst = acc[nt];
    }
}

// ================= fallback (round-1 scalar path) =================
__global__ void transpose_weight_kernel(const float* __restrict__ w,
                                        float* __restrict__ wt) {
    int i = blockIdx.x * 256 + threadIdx.x;
    if (i < CC * KK * OO) {
        int o = i & 63;
        int ck = i >> 6;
        wt[i] = w[o * (CC * KK) + ck];
    }
}

__global__ __launch_bounds__(256)
void deform_conv_kernel(const float* __restrict__ data,
                        const float* __restrict__ offset,
                        const float* __restrict__ wt,
                        float* __restrict__ out) {
    const int tid = threadIdx.x;
    const int wo = tid & 127;
    int ohalf = tid >> 7;
    ohalf = __builtin_amdgcn_readfirstlane(ohalf);
    const int row = blockIdx.x;
    const int b = row >> 7;
    const int ho = row & 127;
    int abyte[KK][4];
    float wgt[KK][4];
    const float* offBase = offset + ((size_t)b * 18) * PLANE + ho * WW + wo;
#pragma unroll
    for (int k = 0; k < KK; ++k) {
        float oy = offBase[(2 * k) * PLANE];
        float ox = offBase[(2 * k + 1) * PLANE];
        float py = oy + (float)(ho - 1 + k / 3);
        float px = ox + (float)(wo - 1 + k % 3);
        float y0f = floorf(py);
        float x0f = floorf(px);
        float wy1 = py - y0f, wx1 = px - x0f;
        float wy0 = 1.f - wy1, wx0 = 1.f - wx1;
        int y0 = (int)y0f, x0 = (int)x0f;
        int y1 = y0 + 1, x1 = x0 + 1;
        float my0 = (y0 >= 0 && y0 < HH) ? 1.f : 0.f;
        float my1 = (y1 >= 0 && y1 < HH) ? 1.f : 0.f;
        float mx0 = (x0 >= 0 && x0 < WW) ? 1.f : 0.f;
        float mx1 = (x1 >= 0 && x1 < WW) ? 1.f : 0.f;
        int yc0 = min(max(y0, 0), HH - 1);
        int yc1 = min(max(y1, 0), HH - 1);
        int xc0 = min(max(x0, 0), WW - 1);
        int xc1 = min(max(x1, 0), WW - 1);
        abyte[k][0] = (yc0 * WW + xc0) * 4;
        abyte[k][1] = (yc0 * WW + xc1) * 4;
        abyte[k][2] = (yc1 * WW + xc0) * 4;
        abyte[k][3] = (yc1 * WW + xc1) * 4;
        wgt[k][0] = wy0 * wx0 * my0 * mx0;
        wgt[k][1] = wy0 * wx1 * my0 * mx1;
        wgt[k][2] = wy1 * wx0 * my1 * mx0;
        wgt[k][3] = wy1 * wx1 * my1 * mx1;
    }
    float acc[32];
#pragma unroll
    for (int j = 0; j < 32; ++j) acc[j] = 0.f;
    const float* planeBase = data + (size_t)b * CC * PLANE;
    const float4* wt4base = (const float4*)wt + ohalf * 8;
    for (int c = 0; c < CC; ++c) {
        const char* pc = (const char*)(planeBase + c * PLANE);
#pragma unroll
        for (int k = 0; k < KK; ++k) {
            float v00 = *(const float*)(pc + abyte[k][0]);
            float v01 = *(const float*)(pc + abyte[k][1]);
            float v10 = *(const float*)(pc + abyte[k][2]);
            float v11 = *(const float*)(pc + abyte[k][3]);
            float s = wgt[k][0] * v00 + wgt[k][1] * v01 +
                      wgt[k][2] * v10 + wgt[k][3] * v11;
            const float4* wp = wt4base + (c * KK + k) * 16;
#pragma unroll
            for (int j = 0; j < 8; ++j) {
                float4 wv = wp[j];
                acc[4 * j + 0] += s * wv.x;
                acc[4 * j + 1] += s * wv.y;
                acc[4 * j + 2] += s * wv.z;
                acc[4 * j + 3] += s * wv.w;
            }
        }
    }
    float* outp = out + ((size_t)b * OO + ohalf * 32) * PLANE + ho * WW + wo;
#pragma unroll
    for (int j = 0; j < 32; ++j) outp[j * PLANE] = acc[j];
}

extern "C" void kernel_launch(void* const* d_in, const int* in_sizes, int n_in,
                              void* d_out, int out_size, void* d_ws, size_t ws_size,
                              hipStream_t stream) {
    const float* data = (const float*)d_in[0];    // (8,64,128,128) f32
    const float* offset = (const float*)d_in[1];  // (8,18,128,128) f32
    const float* weight = (const float*)d_in[2];  // (64,64,3,3) f32
    float* out = (float*)d_out;                   // (8,64,128,128) f32

    const size_t DATA_T_BYTES = (size_t)8 * 2 * 128 * 128 * 64;   // 16,777,216 (split-half f16)
    const size_t WT4_BYTES = (size_t)2 * KK * 4 * 64 * 8 * 2;     // 73,728

    if (ws_size >= DATA_T_BYTES + WT4_BYTES) {
        unsigned short* dataT = (unsigned short*)d_ws;
        _Float16* wt4 = (_Float16*)((char*)d_ws + DATA_T_BYTES);
        prep_kernel<<<2048 + 144, 256, 0, stream>>>(data, weight, dataT, wt4);
        deform_mfma_kernel<<<8 * HH, 512, 0, stream>>>(dataT, offset, wt4, out);
    } else {
        float* wt = (float*)d_ws;
        int nw = CC * KK * OO;
        transpose_weight_kernel<<<(nw + 255) / 256, 256, 0, stream>>>(weight, wt);
        deform_conv_kernel<<<8 * HH, 256, 0, stream>>>(data, offset, wt, out);
    }
}

// Round 7
// 129.491 us; speedup vs baseline: 1.6934x; 1.6934x over previous
//
#include <hip/hip_runtime.h>

#define HH 128
#define WW 128
#define CC 64
#define OO 64
#define KK 9
#define PLANE (HH * WW)

#define BAND 11
#define PXB 72                              // padded pixel stride in LDS (bank stagger)
#define BAND_B (BAND * 128 * PXB)           // 101376
#define POOL_SLOTS 64
#define POOL_OFF BAND_B
#define POOL_B (POOL_SLOTS * 144)           // 9216 (2px windows, 72B stride)
#define DESC_OFF (POOL_OFF + POOL_B)        // 110592
#define LDS_TOTAL (DESC_OFF + KK * 256 * 16)// 147456

typedef _Float16 half8v __attribute__((ext_vector_type(8)));
typedef _Float16 half2v __attribute__((ext_vector_type(2)));
typedef float floatx4 __attribute__((ext_vector_type(4)));

__device__ __forceinline__ unsigned pkpair(float a, float b) {
    return __builtin_bit_cast(unsigned, __builtin_amdgcn_cvt_pkrtz(a, b));
}
__device__ __forceinline__ half2v h2(unsigned u) {
    return __builtin_bit_cast(half2v, u);
}

// ---------- combined prep: blocks [0,2048) NCHW->split-half NHWC f16; [2048,2192) weight ----------
__global__ __launch_bounds__(256)
void prep_kernel(const float* __restrict__ in, const float* __restrict__ wsrc,
                 unsigned short* __restrict__ outT, _Float16* __restrict__ wt4) {
    __shared__ unsigned tile[64 * 36];
    int blk = blockIdx.x;
    int t = threadIdx.x;
    if (blk < 2048) {
        int b = blk & 7;                     // XCD swizzle
        int rest = blk >> 3;
        int y = rest >> 1;
        int xh = rest & 1;
        int p = t & 63;
        int cg = t >> 6;                     // 0..3
        const float* src = in + (size_t)(b * 64) * PLANE + y * WW + xh * 64 + p;
#pragma unroll
        for (int i = 0; i < 8; ++i) {
            int c0 = cg * 16 + 2 * i;
            float v0 = src[(size_t)c0 * PLANE];
            float v1 = src[(size_t)(c0 + 1) * PLANE];
            unsigned lo = __builtin_bit_cast(unsigned short, (_Float16)v0);
            unsigned hi = __builtin_bit_cast(unsigned short, (_Float16)v1);
            tile[p * 36 + (c0 >> 1)] = lo | (hi << 16);
        }
        __syncthreads();
        int p2 = t >> 2;                     // px 0..63
        int q = t & 3;                       // ch-16 group
        const unsigned* s = &tile[p2 * 36 + q * 8];
        uint4 w0 = *(const uint4*)s;
        uint4 w1 = *(const uint4*)(s + 4);
        int half = q >> 1;
        char* dst = (char*)outT + ((size_t)(b * 2 + half) << 20)
                  + (size_t)(y * 128 + xh * 64 + p2) * 64 + (q & 1) * 32;
        *(uint4*)dst = w0;
        *(uint4*)(dst + 16) = w1;
    } else {
        int idx = (blk - 2048) * 256 + t;
        if (idx < 2 * KK * 4 * 64 * 8) {
            int j = idx & 7;
            int lane = (idx >> 3) & 63;
            int nt = (idx >> 9) & 3;
            int pk = idx >> 11;              // pass*9 + k
            int k = pk % 9;
            int pass = pk / 9;
            int o = nt * 16 + (lane & 15);
            int c = pass * 32 + (lane >> 4) * 8 + j;
            wt4[idx] = (_Float16)wsrc[(o * 64 + c) * 9 + k];
        }
    }
}

// ---------- main: r2 layout (PXB=72 band, 2-offset descriptors) + latency fixes ----------
// 1024 threads = 16 waves, single resident block (LDS 147KB). vs r2:
//  (1) k-loop fully unrolled with 1-deep rolling desc+tap prefetch (named regs, no arrays)
//      so the 18 serial desc->tap LDS round-trips pipeline instead of stalling each k;
//  (2) T14 async staging: band global loads issued early (before desc build / before
//      gather0), LDS writes deferred to after the barrier -- HBM/L2 latency hides under
//      compute instead of sitting in a serial stage phase.
__global__ __launch_bounds__(1024, 4)
void deform_mfma_kernel(const unsigned short* __restrict__ dataT,
                        const float* __restrict__ offset,
                        const _Float16* __restrict__ wt4,
                        float* __restrict__ out) {
    __shared__ __align__(16) char SB[LDS_TOTAL];
    __shared__ unsigned ovfSrc[POOL_SLOTS];
    __shared__ int ovfCnt;

    const int t = threadIdx.x;
    const int lane = t & 63;
    const int w = t >> 6;                // wave 0..15
    const unsigned quad = (unsigned)((lane >> 4) & 3);
    const int l15 = lane & 15;
    const int raw = blockIdx.x;
    const int b = raw & 7;               // XCD-aligned batch
    const int ho0 = (raw >> 3) * 2;      // row pair
    const int bs = min(max(ho0 - 4, 0), HH - BAND);

    if (t == 0) ovfCnt = 0;
    __syncthreads();

    // ---- T14: issue pass-0 band loads NOW; written to LDS after desc build ----
    const char* gh0 = (const char*)dataT + ((size_t)(b * 2 + 0) << 20);
    const char* gs0 = gh0 + (unsigned)(bs * 8192);
    uint4 g0 = *(const uint4*)(gs0 + (size_t)(0 * 1024 + t) * 16);
    uint4 g1 = *(const uint4*)(gs0 + (size_t)(1 * 1024 + t) * 16);
    uint4 g2 = *(const uint4*)(gs0 + (size_t)(2 * 1024 + t) * 16);
    uint4 g3 = *(const uint4*)(gs0 + (size_t)(3 * 1024 + t) * 16);
    uint4 g4 = *(const uint4*)(gs0 + (size_t)(4 * 1024 + t) * 16);
    uint4 g5;
    if (t < 512) g5 = *(const uint4*)(gs0 + (size_t)(5120 + t) * 16);

    // ---- descriptors: 2304 (k, p) units over 1024 threads (r2 scheme) ----
#pragma unroll
    for (int i = 0; i < 3; ++i) {
        int u = i * 1024 + t;
        if (u < KK * 256) {
            int p = u & 255;
            int k = u >> 8;
            int x = p & 127;
            int ho = ho0 + (p >> 7);
            const float* offp = offset + ((size_t)(b * 18) + 2 * k) * PLANE + ho * WW + x;
            float oy = offp[0];
            float ox = offp[PLANE];
            float py = (float)(ho - 1 + k / 3) + oy;
            float pxx = (float)(x - 1 + k % 3) + ox;
            float y0f = floorf(py);
            float x0f = floorf(pxx);
            float fy = py - y0f;
            float fx = pxx - x0f;
            int y0 = (int)y0f, x0 = (int)x0f;
            int y1 = y0 + 1, x1 = x0 + 1;
            float wy0 = (1.f - fy) * ((y0 >= 0 && y0 < HH) ? 1.f : 0.f);
            float wy1 = fy * ((y1 >= 0 && y1 < HH) ? 1.f : 0.f);
            float wx0 = (1.f - fx) * ((x0 >= 0 && x0 < WW) ? 1.f : 0.f);
            float wx1 = fx * ((x1 >= 0 && x1 < WW) ? 1.f : 0.f);
            int yc0 = min(max(y0, 0), HH - 1);
            int yc1 = min(max(y1, 0), HH - 1);
            int x_lo = min(max(x0, 0), WW - 2);
            float wA = ((x0 == x_lo) ? wx0 : 0.f) + ((x1 == x_lo) ? wx1 : 0.f);
            float wB = ((x0 == x_lo + 1) ? wx0 : 0.f) + ((x1 == x_lo + 1) ? wx1 : 0.f);

            unsigned off0, off1;
            {
                int r = yc0 - bs;
                if (wy0 == 0.f) off0 = (unsigned)(x_lo * PXB);
                else if ((unsigned)r < BAND) off0 = (unsigned)((r * 128 + x_lo) * PXB);
                else {
                    int slot = atomicAdd(&ovfCnt, 1);
                    if (slot < POOL_SLOTS) {
                        ovfSrc[slot] = (unsigned)((yc0 * 128 + x_lo) * 64);
                        off0 = (unsigned)(POOL_OFF + slot * 144);
                    } else {
                        int rc = min(max(r, 0), BAND - 1);
                        off0 = (unsigned)((rc * 128 + x_lo) * PXB);
                    }
                }
            }
            {
                int r = yc1 - bs;
                if (wy1 == 0.f) off1 = (unsigned)(x_lo * PXB);
                else if ((unsigned)r < BAND) off1 = (unsigned)((r * 128 + x_lo) * PXB);
                else {
                    int slot = atomicAdd(&ovfCnt, 1);
                    if (slot < POOL_SLOTS) {
                        ovfSrc[slot] = (unsigned)((yc1 * 128 + x_lo) * 64);
                        off1 = (unsigned)(POOL_OFF + slot * 144);
                    } else {
                        int rc = min(max(r, 0), BAND - 1);
                        off1 = (unsigned)((rc * 128 + x_lo) * PXB);
                    }
                }
            }
            uint4 d;
            d.x = (off0 >> 3) | ((off1 >> 3) << 16);   // both multiples of 8, < 2^16 after /8
            d.y = pkpair(wy0 * wA, wy0 * wB);          // (w00, w01)
            d.z = pkpair(wy1 * wA, wy1 * wB);          // (w10, w11)
            d.w = 0;
            *(uint4*)(SB + DESC_OFF + (size_t)(k * 256 + p) * 16) = d;
        }
    }

    // ---- write staged pass-0 band (LDS region disjoint from descriptors) ----
    {
#pragma unroll
        for (int i = 0; i < 5; ++i) {
            unsigned u = (unsigned)(i * 1024 + t);
            uint4 v = (i == 0) ? g0 : (i == 1) ? g1 : (i == 2) ? g2 : (i == 3) ? g3 : g4;
            *(uint4*)(SB + (u >> 2) * PXB + (u & 3) * 16) = v;
        }
        if (t < 512) {
            unsigned u = (unsigned)(5120 + t);
            *(uint4*)(SB + (u >> 2) * PXB + (u & 3) * 16) = g5;
        }
    }
    __syncthreads();
    const int cnt = min(ovfCnt, POOL_SLOTS);

    // ---- overflow pool, pass 0 (rare; block-uniform branch) ----
    if (cnt > 0) {
        if (t < cnt * 8) {
            int s = t >> 3, j = t & 7, ps = j >> 2, q = j & 3;
            uint4 v = *(const uint4*)(gh0 + ovfSrc[s] + ps * 64 + q * 16);
            *(uint4*)(SB + POOL_OFF + s * 144 + ps * 72 + q * 16) = v;
        }
        __syncthreads();
    }

    // ---- T14: issue pass-1 band loads; they fly during gather pass 0 ----
    const char* gh1 = (const char*)dataT + ((size_t)(b * 2 + 1) << 20);
    const char* gs1 = gh1 + (unsigned)(bs * 8192);
    uint4 h0 = *(const uint4*)(gs1 + (size_t)(0 * 1024 + t) * 16);
    uint4 h1 = *(const uint4*)(gs1 + (size_t)(1 * 1024 + t) * 16);
    uint4 h2x = *(const uint4*)(gs1 + (size_t)(2 * 1024 + t) * 16);
    uint4 h3 = *(const uint4*)(gs1 + (size_t)(3 * 1024 + t) * 16);
    uint4 h4 = *(const uint4*)(gs1 + (size_t)(4 * 1024 + t) * 16);
    uint4 h5;
    if (t < 512) h5 = *(const uint4*)(gs1 + (size_t)(5120 + t) * 16);

    floatx4 acc[4];
#pragma unroll
    for (int nt = 0; nt < 4; ++nt)
        acc[nt] = (floatx4){0.f, 0.f, 0.f, 0.f};

    const unsigned qoff = quad * 16;
    const int p = w * 16 + l15;

    // ---- gather + MFMA, unrolled with 1-deep rolling prefetch ----
    auto gather_pass = [&](int pass) {
        uint4 d0 = *(const uint4*)(SB + DESC_OFF + (size_t)(0 * 256 + p) * 16);
        unsigned off0 = (d0.x & 0xffffu) << 3;
        unsigned off1 = (d0.x >> 16) << 3;
        uint4 c00 = *(const uint4*)(SB + off0 + qoff);
        uint4 c01 = *(const uint4*)(SB + off0 + 72 + qoff);
        uint4 c10 = *(const uint4*)(SB + off1 + qoff);
        uint4 c11 = *(const uint4*)(SB + off1 + 72 + qoff);
        unsigned wy = d0.y, wz = d0.z;
#pragma unroll
        for (int k = 0; k < KK; ++k) {
            uint4 bfr[4];
            const uint4* wk = (const uint4*)wt4 + (size_t)((pass * 9 + k) * 4) * 64 + lane;
#pragma unroll
            for (int nt = 0; nt < 4; ++nt) bfr[nt] = wk[nt * 64];

            uint4 n00, n01, n10, n11;
            unsigned nwy, nwz;
            if (k + 1 < KK) {
                uint4 dn = *(const uint4*)(SB + DESC_OFF + (size_t)((k + 1) * 256 + p) * 16);
                unsigned no0 = (dn.x & 0xffffu) << 3;
                unsigned no1 = (dn.x >> 16) << 3;
                n00 = *(const uint4*)(SB + no0 + qoff);
                n01 = *(const uint4*)(SB + no0 + 72 + qoff);
                n10 = *(const uint4*)(SB + no1 + qoff);
                n11 = *(const uint4*)(SB + no1 + 72 + qoff);
                nwy = dn.y; nwz = dn.z;
            }

            half2v wv0 = h2(wy), wv1 = h2(wz);
            half2v h00 = __builtin_shufflevector(wv0, wv0, 0, 0);
            half2v h01 = __builtin_shufflevector(wv0, wv0, 1, 1);
            half2v h10 = __builtin_shufflevector(wv1, wv1, 0, 0);
            half2v h11 = __builtin_shufflevector(wv1, wv1, 1, 1);
            half2v s0 = h2(c00.x) * h00 + h2(c01.x) * h01 + h2(c10.x) * h10 + h2(c11.x) * h11;
            half2v s1 = h2(c00.y) * h00 + h2(c01.y) * h01 + h2(c10.y) * h10 + h2(c11.y) * h11;
            half2v s2 = h2(c00.z) * h00 + h2(c01.z) * h01 + h2(c10.z) * h10 + h2(c11.z) * h11;
            half2v s3 = h2(c00.w) * h00 + h2(c01.w) * h01 + h2(c10.w) * h10 + h2(c11.w) * h11;
            uint4 sv = make_uint4(__builtin_bit_cast(unsigned, s0),
                                  __builtin_bit_cast(unsigned, s1),
                                  __builtin_bit_cast(unsigned, s2),
                                  __builtin_bit_cast(unsigned, s3));
            half8v afrag = __builtin_bit_cast(half8v, sv);   // A[m=l15][c=quad*8+j]
#pragma unroll
            for (int nt = 0; nt < 4; ++nt)
                acc[nt] = __builtin_amdgcn_mfma_f32_16x16x32_f16(
                    afrag, __builtin_bit_cast(half8v, bfr[nt]), acc[nt], 0, 0, 0);

            if (k + 1 < KK) {
                c00 = n00; c01 = n01; c10 = n10; c11 = n11;
                wy = nwy; wz = nwz;
            }
        }
    };

    gather_pass(0);
    __syncthreads();                         // band reads done before overwrite

    // ---- write staged pass-1 band + pool ----
    {
#pragma unroll
        for (int i = 0; i < 5; ++i) {
            unsigned u = (unsigned)(i * 1024 + t);
            uint4 v = (i == 0) ? h0 : (i == 1) ? h1 : (i == 2) ? h2x : (i == 3) ? h3 : h4;
            *(uint4*)(SB + (u >> 2) * PXB + (u & 3) * 16) = v;
        }
        if (t < 512) {
            unsigned u = (unsigned)(5120 + t);
            *(uint4*)(SB + (u >> 2) * PXB + (u & 3) * 16) = h5;
        }
        if (t < cnt * 8) {
            int s = t >> 3, j = t & 7, ps = j >> 2, q = j & 3;
            uint4 v = *(const uint4*)(gh1 + ovfSrc[s] + ps * 64 + q * 16);
            *(uint4*)(SB + POOL_OFF + s * 144 + ps * 72 + q * 16) = v;
        }
    }
    __syncthreads();

    gather_pass(1);

    // ---- epilogue: D col=lane&15 (=o), row=quad*4+reg (=pixel) ----
#pragma unroll
    for (int nt = 0; nt < 4; ++nt) {
        int o = nt * 16 + l15;
        int pp = w * 16 + (int)quad * 4;
        int ho = ho0 + (pp >> 7);
        int x = pp & 127;
        float* dst = out + (size_t)(b * 64 + o) * PLANE + ho * 128 + x;
        *(floatx4*)dst = acc[nt];
    }
}

// ================= fallback (round-1 scalar path) =================
__global__ void transpose_weight_kernel(const float* __restrict__ w,
                                        float* __restrict__ wt) {
    int i = blockIdx.x * 256 + threadIdx.x;
    if (i < CC * KK * OO) {
        int o = i & 63;
        int ck = i >> 6;
        wt[i] = w[o * (CC * KK) + ck];
    }
}

__global__ __launch_bounds__(256)
void deform_conv_kernel(const float* __restrict__ data,
                        const float* __restrict__ offset,
                        const float* __restrict__ wt,
                        float* __restrict__ out) {
    const int tid = threadIdx.x;
    const int wo = tid & 127;
    int ohalf = tid >> 7;
    ohalf = __builtin_amdgcn_readfirstlane(ohalf);
    const int row = blockIdx.x;
    const int b = row >> 7;
    const int ho = row & 127;
    int abyte[KK][4];
    float wgt[KK][4];
    const float* offBase = offset + ((size_t)b * 18) * PLANE + ho * WW + wo;
#pragma unroll
    for (int k = 0; k < KK; ++k) {
        float oy = offBase[(2 * k) * PLANE];
        float ox = offBase[(2 * k + 1) * PLANE];
        float py = oy + (float)(ho - 1 + k / 3);
        float px = ox + (float)(wo - 1 + k % 3);
        float y0f = floorf(py);
        float x0f = floorf(px);
        float wy1 = py - y0f, wx1 = px - x0f;
        float wy0 = 1.f - wy1, wx0 = 1.f - wx1;
        int y0 = (int)y0f, x0 = (int)x0f;
        int y1 = y0 + 1, x1 = x0 + 1;
        float my0 = (y0 >= 0 && y0 < HH) ? 1.f : 0.f;
        float my1 = (y1 >= 0 && y1 < HH) ? 1.f : 0.f;
        float mx0 = (x0 >= 0 && x0 < WW) ? 1.f : 0.f;
        float mx1 = (x1 >= 0 && x1 < WW) ? 1.f : 0.f;
        int yc0 = min(max(y0, 0), HH - 1);
        int yc1 = min(max(y1, 0), HH - 1);
        int xc0 = min(max(x0, 0), WW - 1);
        int xc1 = min(max(x1, 0), WW - 1);
        abyte[k][0] = (yc0 * WW + xc0) * 4;
        abyte[k][1] = (yc0 * WW + xc1) * 4;
        abyte[k][2] = (yc1 * WW + xc0) * 4;
        abyte[k][3] = (yc1 * WW + xc1) * 4;
        wgt[k][0] = wy0 * wx0 * my0 * mx0;
        wgt[k][1] = wy0 * wx1 * my0 * mx1;
        wgt[k][2] = wy1 * wx0 * my1 * mx0;
        wgt[k][3] = wy1 * wx1 * my1 * mx1;
    }
    float acc[32];
#pragma unroll
    for (int j = 0; j < 32; ++j) acc[j] = 0.f;
    const float* planeBase = data + (size_t)b * CC * PLANE;
    const float4* wt4base = (const float4*)wt + ohalf * 8;
    for (int c = 0; c < CC; ++c) {
        const char* pc = (const char*)(planeBase + c * PLANE);
#pragma unroll
        for (int k = 0; k < KK; ++k) {
            float v00 = *(const float*)(pc + abyte[k][0]);
            float v01 = *(const float*)(pc + abyte[k][1]);
            float v10 = *(const float*)(pc + abyte[k][2]);
            float v11 = *(const float*)(pc + abyte[k][3]);
            float s = wgt[k][0] * v00 + wgt[k][1] * v01 +
                      wgt[k][2] * v10 + wgt[k][3] * v11;
            const float4* wp = wt4base + (c * KK + k) * 16;
#pragma unroll
            for (int j = 0; j < 8; ++j) {
                float4 wv = wp[j];
                acc[4 * j + 0] += s * wv.x;
                acc[4 * j + 1] += s * wv.y;
                acc[4 * j + 2] += s * wv.z;
                acc[4 * j + 3] += s * wv.w;
            }
        }
    }
    float* outp = out + ((size_t)b * OO + ohalf * 32) * PLANE + ho * WW + wo;
#pragma unroll
    for (int j = 0; j < 32; ++j) outp[j * PLANE] = acc[j];
}

extern "C" void kernel_launch(void* const* d_in, const int* in_sizes, int n_in,
                              void* d_out, int out_size, void* d_ws, size_t ws_size,
                              hipStream_t stream) {
    const float* data = (const float*)d_in[0];    // (8,64,128,128) f32
    const float* offset = (const float*)d_in[1];  // (8,18,128,128) f32
    const float* weight = (const float*)d_in[2];  // (64,64,3,3) f32
    float* out = (float*)d_out;                   // (8,64,128,128) f32

    const size_t DATA_T_BYTES = (size_t)8 * 2 * 128 * 128 * 64;   // 16,777,216 (split-half f16)
    const size_t WT4_BYTES = (size_t)2 * KK * 4 * 64 * 8 * 2;     // 73,728

    if (ws_size >= DATA_T_BYTES + WT4_BYTES) {
        unsigned short* dataT = (unsigned short*)d_ws;
        _Float16* wt4 = (_Float16*)((char*)d_ws + DATA_T_BYTES);
        prep_kernel<<<2048 + 144, 256, 0, stream>>>(data, weight, dataT, wt4);
        deform_mfma_kernel<<<8 * (HH / 2), 1024, 0, stream>>>(dataT, offset, wt4, out);
    } else {
        float* wt = (float*)d_ws;
        int nw = CC * KK * OO;
        transpose_weight_kernel<<<(nw + 255) / 256, 256, 0, stream>>>(weight, wt);
        deform_conv_kernel<<<8 * HH, 256, 0, stream>>>(data, offset, wt, out);
    }
}

// Round 8
// 128.750 us; speedup vs baseline: 1.7032x; 1.0058x over previous
//
#include <hip/hip_runtime.h>

#define HH 128
#define WW 128
#define CC 64
#define OO 64
#define KK 9
#define PLANE (HH * WW)

#define XBAND 78                            // band cols: 64 outputs + 7 halo each side
#define YBAND 10                            // band rows: [ho0-4, ho0+5]
#define PXB 72                              // padded pixel stride in LDS (bank stagger)
#define BAND_B (YBAND * XBAND * PXB)        // 56160
#define POOL_SLOTS 32
#define POOL_OFF BAND_B
#define POOL_B (POOL_SLOTS * 144)           // 4608 (2px windows, 72B stride)
#define DESC_OFF (POOL_OFF + POOL_B)        // 60768
#define LDS_TOTAL (DESC_OFF + KK * 128 * 16)// 79200 -> 2 blocks/CU

typedef _Float16 half8v __attribute__((ext_vector_type(8)));
typedef _Float16 half2v __attribute__((ext_vector_type(2)));
typedef float floatx4 __attribute__((ext_vector_type(4)));

__device__ __forceinline__ unsigned pkpair(float a, float b) {
    return __builtin_bit_cast(unsigned, __builtin_amdgcn_cvt_pkrtz(a, b));
}
__device__ __forceinline__ half2v h2(unsigned u) {
    return __builtin_bit_cast(half2v, u);
}

// ---------- combined prep: blocks [0,2048) NCHW->split-half NHWC f16; [2048,2192) weight ----------
__global__ __launch_bounds__(256)
void prep_kernel(const float* __restrict__ in, const float* __restrict__ wsrc,
                 unsigned short* __restrict__ outT, _Float16* __restrict__ wt4) {
    __shared__ unsigned tile[64 * 36];
    int blk = blockIdx.x;
    int t = threadIdx.x;
    if (blk < 2048) {
        int b = blk & 7;                     // XCD swizzle
        int rest = blk >> 3;
        int y = rest >> 1;
        int xh = rest & 1;
        int p = t & 63;
        int cg = t >> 6;                     // 0..3
        const float* src = in + (size_t)(b * 64) * PLANE + y * WW + xh * 64 + p;
#pragma unroll
        for (int i = 0; i < 8; ++i) {
            int c0 = cg * 16 + 2 * i;
            float v0 = src[(size_t)c0 * PLANE];
            float v1 = src[(size_t)(c0 + 1) * PLANE];
            unsigned lo = __builtin_bit_cast(unsigned short, (_Float16)v0);
            unsigned hi = __builtin_bit_cast(unsigned short, (_Float16)v1);
            tile[p * 36 + (c0 >> 1)] = lo | (hi << 16);
        }
        __syncthreads();
        int p2 = t >> 2;                     // px 0..63
        int q = t & 3;                       // ch-16 group
        const unsigned* s = &tile[p2 * 36 + q * 8];
        uint4 w0 = *(const uint4*)s;
        uint4 w1 = *(const uint4*)(s + 4);
        int half = q >> 1;
        char* dst = (char*)outT + ((size_t)(b * 2 + half) << 20)
                  + (size_t)(y * 128 + xh * 64 + p2) * 64 + (q & 1) * 32;
        *(uint4*)dst = w0;
        *(uint4*)(dst + 16) = w1;
    } else {
        int idx = (blk - 2048) * 256 + t;
        if (idx < 2 * KK * 4 * 64 * 8) {
            int j = idx & 7;
            int lane = (idx >> 3) & 63;
            int nt = (idx >> 9) & 3;
            int pk = idx >> 11;              // pass*9 + k
            int k = pk % 9;
            int pass = pk / 9;
            int o = nt * 16 + (lane & 15);
            int c = pass * 32 + (lane >> 4) * 8 + j;
            wt4[idx] = (_Float16)wsrc[(o * 64 + c) * 9 + k];
        }
    }
}

// ---------- main: half-row blocks (64 cols), 79KB LDS -> 2 independent blocks/CU ----------
// Same proven PXB=72 band + 2-offset descriptors as r2/r7, but split in x so two blocks
// co-reside per CU: one block's desc-build/staging overlaps the other's gather, filling
// the ~30% barrier-lockstep idle the single-block versions could not.
__global__ __launch_bounds__(512, 4)
void deform_mfma_kernel(const unsigned short* __restrict__ dataT,
                        const float* __restrict__ offset,
                        const _Float16* __restrict__ wt4,
                        float* __restrict__ out) {
    __shared__ __align__(16) char SB[LDS_TOTAL];
    __shared__ unsigned ovfSrc[POOL_SLOTS];
    __shared__ int ovfCnt;

    const int t = threadIdx.x;
    const int lane = t & 63;
    const int w = t >> 6;                // wave 0..7
    const unsigned quad = (unsigned)((lane >> 4) & 3);
    const int l15 = lane & 15;
    const int raw = blockIdx.x;
    const int b = raw & 7;               // XCD-aligned batch
    const int rest = raw >> 3;           // 0..127
    const int xh = rest & 1;             // column half
    const int ho0 = (rest >> 1) * 2;     // row pair
    const int cx0 = xh * 64;
    const int bs = min(max(ho0 - 4, 0), HH - YBAND);

    if (t == 0) ovfCnt = 0;
    __syncthreads();

    int cnt = 0;

    // ---- descriptors: 1152 (k, p) units over 512 threads ----
#pragma unroll
    for (int i = 0; i < 3; ++i) {
        int u = i * 512 + t;
        if (u < KK * 128) {
            int p = u & 127;
            int k = u >> 7;
            int x = cx0 + (p & 63);
            int ho = ho0 + (p >> 6);
            const float* offp = offset + ((size_t)(b * 18) + 2 * k) * PLANE + ho * WW + x;
            float oy = offp[0];
            float ox = offp[PLANE];
            float py = (float)(ho - 1 + k / 3) + oy;
            float pxx = (float)(x - 1 + k % 3) + ox;
            float y0f = floorf(py);
            float x0f = floorf(pxx);
            float fy = py - y0f;
            float fx = pxx - x0f;
            int y0 = (int)y0f, x0 = (int)x0f;
            int y1 = y0 + 1, x1 = x0 + 1;
            float wy0 = (1.f - fy) * ((y0 >= 0 && y0 < HH) ? 1.f : 0.f);
            float wy1 = fy * ((y1 >= 0 && y1 < HH) ? 1.f : 0.f);
            float wx0 = (1.f - fx) * ((x0 >= 0 && x0 < WW) ? 1.f : 0.f);
            float wx1 = fx * ((x1 >= 0 && x1 < WW) ? 1.f : 0.f);
            int yc0 = min(max(y0, 0), HH - 1);
            int yc1 = min(max(y1, 0), HH - 1);
            int x_lo = min(max(x0, 0), WW - 2);
            float wA = ((x0 == x_lo) ? wx0 : 0.f) + ((x1 == x_lo) ? wx1 : 0.f);
            float wB = ((x0 == x_lo + 1) ? wx0 : 0.f) + ((x1 == x_lo + 1) ? wx1 : 0.f);

            int s_lo = x_lo - cx0 + 7;               // band col of x_lo
            int s_safe = min(max(s_lo, 0), XBAND - 2);
            bool col_ok = (s_lo >= 0) && (s_lo <= XBAND - 2);

            unsigned off0, off1;
            {
                int r = yc0 - bs;
                if (wy0 == 0.f) off0 = (unsigned)(s_safe * PXB);
                else if ((unsigned)r < YBAND && col_ok)
                    off0 = (unsigned)((r * XBAND + s_lo) * PXB);
                else {
                    int slot = atomicAdd(&ovfCnt, 1);
                    if (slot < POOL_SLOTS) {
                        ovfSrc[slot] = (unsigned)((yc0 * 128 + x_lo) * 64);
                        off0 = (unsigned)(POOL_OFF + slot * 144);
                    } else {
                        int rc = min(max(r, 0), YBAND - 1);
                        off0 = (unsigned)((rc * XBAND + s_safe) * PXB);
                    }
                }
            }
            {
                int r = yc1 - bs;
                if (wy1 == 0.f) off1 = (unsigned)(s_safe * PXB);
                else if ((unsigned)r < YBAND && col_ok)
                    off1 = (unsigned)((r * XBAND + s_lo) * PXB);
                else {
                    int slot = atomicAdd(&ovfCnt, 1);
                    if (slot < POOL_SLOTS) {
                        ovfSrc[slot] = (unsigned)((yc1 * 128 + x_lo) * 64);
                        off1 = (unsigned)(POOL_OFF + slot * 144);
                    } else {
                        int rc = min(max(r, 0), YBAND - 1);
                        off1 = (unsigned)((rc * XBAND + s_safe) * PXB);
                    }
                }
            }
            uint4 d;
            d.x = (off0 >> 3) | ((off1 >> 3) << 16);   // both multiples of 8, fit 16b after /8
            d.y = pkpair(wy0 * wA, wy0 * wB);          // (w00, w01)
            d.z = pkpair(wy1 * wA, wy1 * wB);          // (w10, w11)
            d.w = 0;
            *(uint4*)(SB + DESC_OFF + (size_t)(k * 128 + p) * 16) = d;
        }
    }

    // ---- band staging: 780 px (10 rows x 78 cols) = 3120 16B units ----
    auto stage_band = [&](const char* gh) {
#pragma unroll
        for (int i = 0; i < 6; ++i) {
            int u = i * 512 + t;
            int px = u >> 2, q = u & 3;
            int r = px / XBAND;
            int c = px - r * XBAND;
            int gcol = min(max(cx0 - 7 + c, 0), 127);
            uint4 v = *(const uint4*)(gh + (size_t)(((bs + r) * 128 + gcol) * 64) + q * 16);
            *(uint4*)(SB + (size_t)(px * PXB) + q * 16) = v;
        }
        if (t < 48) {
            int u = 3072 + t;
            int px = u >> 2, q = u & 3;
            int r = px / XBAND;
            int c = px - r * XBAND;
            int gcol = min(max(cx0 - 7 + c, 0), 127);
            uint4 v = *(const uint4*)(gh + (size_t)(((bs + r) * 128 + gcol) * 64) + q * 16);
            *(uint4*)(SB + (size_t)(px * PXB) + q * 16) = v;
        }
    };
    auto pool_stage = [&](const char* gh) {
        if (t < cnt * 8) {
            int s = t >> 3, j = t & 7, ps = j >> 2, q = j & 3;
            uint4 v = *(const uint4*)(gh + ovfSrc[s] + ps * 64 + q * 16);
            *(uint4*)(SB + POOL_OFF + s * 144 + ps * 72 + q * 16) = v;
        }
    };

    floatx4 acc[4];
#pragma unroll
    for (int nt = 0; nt < 4; ++nt)
        acc[nt] = (floatx4){0.f, 0.f, 0.f, 0.f};

    const unsigned qoff = quad * 16;
    const int p = w * 16 + l15;

    auto gather = [&](int pass) {
#pragma unroll
        for (int k = 0; k < KK; ++k) {
            uint4 bfr[4];
            const uint4* wk = (const uint4*)wt4 + (size_t)((pass * 9 + k) * 4) * 64 + lane;
#pragma unroll
            for (int nt = 0; nt < 4; ++nt) bfr[nt] = wk[nt * 64];

            uint4 d = *(const uint4*)(SB + DESC_OFF + (size_t)(k * 128 + p) * 16);
            unsigned off0 = (d.x & 0xffffu) << 3;
            unsigned off1 = (d.x >> 16) << 3;
            half2v wv0 = h2(d.y), wv1 = h2(d.z);
            half2v h00 = __builtin_shufflevector(wv0, wv0, 0, 0);
            half2v h01 = __builtin_shufflevector(wv0, wv0, 1, 1);
            half2v h10 = __builtin_shufflevector(wv1, wv1, 0, 0);
            half2v h11 = __builtin_shufflevector(wv1, wv1, 1, 1);
            uint4 v00 = *(const uint4*)(SB + off0 + qoff);
            uint4 v01 = *(const uint4*)(SB + off0 + 72 + qoff);
            uint4 v10 = *(const uint4*)(SB + off1 + qoff);
            uint4 v11 = *(const uint4*)(SB + off1 + 72 + qoff);
            half2v s0 = h2(v00.x) * h00 + h2(v01.x) * h01 + h2(v10.x) * h10 + h2(v11.x) * h11;
            half2v s1 = h2(v00.y) * h00 + h2(v01.y) * h01 + h2(v10.y) * h10 + h2(v11.y) * h11;
            half2v s2 = h2(v00.z) * h00 + h2(v01.z) * h01 + h2(v10.z) * h10 + h2(v11.z) * h11;
            half2v s3 = h2(v00.w) * h00 + h2(v01.w) * h01 + h2(v10.w) * h10 + h2(v11.w) * h11;
            uint4 sv = make_uint4(__builtin_bit_cast(unsigned, s0),
                                  __builtin_bit_cast(unsigned, s1),
                                  __builtin_bit_cast(unsigned, s2),
                                  __builtin_bit_cast(unsigned, s3));
            half8v afrag = __builtin_bit_cast(half8v, sv);   // A[m=l15][c=quad*8+j]
#pragma unroll
            for (int nt = 0; nt < 4; ++nt)
                acc[nt] = __builtin_amdgcn_mfma_f32_16x16x32_f16(
                    afrag, __builtin_bit_cast(half8v, bfr[nt]), acc[nt], 0, 0, 0);
        }
    };

    const char* gh0 = (const char*)dataT + ((size_t)(b * 2 + 0) << 20);
    const char* gh1 = (const char*)dataT + ((size_t)(b * 2 + 1) << 20);

    stage_band(gh0);
    __syncthreads();
    cnt = min(ovfCnt, POOL_SLOTS);
    pool_stage(gh0);
    __syncthreads();
    gather(0);
    __syncthreads();
    stage_band(gh1);
    pool_stage(gh1);
    __syncthreads();
    gather(1);

    // ---- epilogue: D col=lane&15 (=o), row=quad*4+reg (=pixel) ----
#pragma unroll
    for (int nt = 0; nt < 4; ++nt) {
        int o = nt * 16 + l15;
        int pp = w * 16 + (int)quad * 4;
        int ho = ho0 + (pp >> 6);
        int x = cx0 + (pp & 63);
        float* dst = out + (size_t)(b * 64 + o) * PLANE + ho * 128 + x;
        *(floatx4*)dst = acc[nt];
    }
}

// ================= fallback (round-1 scalar path) =================
__global__ void transpose_weight_kernel(const float* __restrict__ w,
                                        float* __restrict__ wt) {
    int i = blockIdx.x * 256 + threadIdx.x;
    if (i < CC * KK * OO) {
        int o = i & 63;
        int ck = i >> 6;
        wt[i] = w[o * (CC * KK) + ck];
    }
}

__global__ __launch_bounds__(256)
void deform_conv_kernel(const float* __restrict__ data,
                        const float* __restrict__ offset,
                        const float* __restrict__ wt,
                        float* __restrict__ out) {
    const int tid = threadIdx.x;
    const int wo = tid & 127;
    int ohalf = tid >> 7;
    ohalf = __builtin_amdgcn_readfirstlane(ohalf);
    const int row = blockIdx.x;
    const int b = row >> 7;
    const int ho = row & 127;
    int abyte[KK][4];
    float wgt[KK][4];
    const float* offBase = offset + ((size_t)b * 18) * PLANE + ho * WW + wo;
#pragma unroll
    for (int k = 0; k < KK; ++k) {
        float oy = offBase[(2 * k) * PLANE];
        float ox = offBase[(2 * k + 1) * PLANE];
        float py = oy + (float)(ho - 1 + k / 3);
        float px = ox + (float)(wo - 1 + k % 3);
        float y0f = floorf(py);
        float x0f = floorf(px);
        float wy1 = py - y0f, wx1 = px - x0f;
        float wy0 = 1.f - wy1, wx0 = 1.f - wx1;
        int y0 = (int)y0f, x0 = (int)x0f;
        int y1 = y0 + 1, x1 = x0 + 1;
        float my0 = (y0 >= 0 && y0 < HH) ? 1.f : 0.f;
        float my1 = (y1 >= 0 && y1 < HH) ? 1.f : 0.f;
        float mx0 = (x0 >= 0 && x0 < WW) ? 1.f : 0.f;
        float mx1 = (x1 >= 0 && x1 < WW) ? 1.f : 0.f;
        int yc0 = min(max(y0, 0), HH - 1);
        int yc1 = min(max(y1, 0), HH - 1);
        int xc0 = min(max(x0, 0), WW - 1);
        int xc1 = min(max(x1, 0), WW - 1);
        abyte[k][0] = (yc0 * WW + xc0) * 4;
        abyte[k][1] = (yc0 * WW + xc1) * 4;
        abyte[k][2] = (yc1 * WW + xc0) * 4;
        abyte[k][3] = (yc1 * WW + xc1) * 4;
        wgt[k][0] = wy0 * wx0 * my0 * mx0;
        wgt[k][1] = wy0 * wx1 * my0 * mx1;
        wgt[k][2] = wy1 * wx0 * my1 * mx0;
        wgt[k][3] = wy1 * wx1 * my1 * mx1;
    }
    float acc[32];
#pragma unroll
    for (int j = 0; j < 32; ++j) acc[j] = 0.f;
    const float* planeBase = data + (size_t)b * CC * PLANE;
    const float4* wt4base = (const float4*)wt + ohalf * 8;
    for (int c = 0; c < CC; ++c) {
        const char* pc = (const char*)(planeBase + c * PLANE);
#pragma unroll
        for (int k = 0; k < KK; ++k) {
            float v00 = *(const float*)(pc + abyte[k][0]);
            float v01 = *(const float*)(pc + abyte[k][1]);
            float v10 = *(const float*)(pc + abyte[k][2]);
            float v11 = *(const float*)(pc + abyte[k][3]);
            float s = wgt[k][0] * v00 + wgt[k][1] * v01 +
                      wgt[k][2] * v10 + wgt[k][3] * v11;
            const float4* wp = wt4base + (c * KK + k) * 16;
#pragma unroll
            for (int j = 0; j < 8; ++j) {
                float4 wv = wp[j];
                acc[4 * j + 0] += s * wv.x;
                acc[4 * j + 1] += s * wv.y;
                acc[4 * j + 2] += s * wv.z;
                acc[4 * j + 3] += s * wv.w;
            }
        }
    }
    float* outp = out + ((size_t)b * OO + ohalf * 32) * PLANE + ho * WW + wo;
#pragma unroll
    for (int j = 0; j < 32; ++j) outp[j * PLANE] = acc[j];
}

extern "C" void kernel_launch(void* const* d_in, const int* in_sizes, int n_in,
                              void* d_out, int out_size, void* d_ws, size_t ws_size,
                              hipStream_t stream) {
    const float* data = (const float*)d_in[0];    // (8,64,128,128) f32
    const float* offset = (const float*)d_in[1];  // (8,18,128,128) f32
    const float* weight = (const float*)d_in[2];  // (64,64,3,3) f32
    float* out = (float*)d_out;                   // (8,64,128,128) f32

    const size_t DATA_T_BYTES = (size_t)8 * 2 * 128 * 128 * 64;   // 16,777,216 (split-half f16)
    const size_t WT4_BYTES = (size_t)2 * KK * 4 * 64 * 8 * 2;     // 73,728

    if (ws_size >= DATA_T_BYTES + WT4_BYTES) {
        unsigned short* dataT = (unsigned short*)d_ws;
        _Float16* wt4 = (_Float16*)((char*)d_ws + DATA_T_BYTES);
        prep_kernel<<<2048 + 144, 256, 0, stream>>>(data, weight, dataT, wt4);
        deform_mfma_kernel<<<8 * HH, 512, 0, stream>>>(dataT, offset, wt4, out);
    } else {
        float* wt = (float*)d_ws;
        int nw = CC * KK * OO;
        transpose_weight_kernel<<<(nw + 255) / 256, 256, 0, stream>>>(weight, wt);
        deform_conv_kernel<<<8 * HH, 256, 0, stream>>>(data, offset, wt, out);
    }
}